// Round 7
// baseline (39.432 us; speedup 1.0000x reference)
//
#include <hip/hip_runtime.h>
#include <math.h>

#define NB 256
#define ND 768
#define MARGIN_F 0.2f
#define NKC 32            // k-chunks per matrix
#define CHF 24            // floats per k-chunk (6 float4)
#define PITCH 32          // LDS row pitch in floats (24 padded to 32 = 8 f4 slots)

// bank-swizzle key per side-local row: A-reads 4 distinct groups, B-reads 2-way (free)
__device__ __forceinline__ int swz(int row) { return ((row >> 3) ^ row) & 7; }

// ---------------- k1: dot-product partial planes [2][32][256][256] + sq norms --------
// bid 0,1: sq-norm blocks (first, so they overlap the compute blocks).
// bid 2..513: 2 matrices x 8 tiles (64x128) x 32 k-chunks; 4x8 register tiling.
__global__ __launch_bounds__(256)
void dist_kernel(const float* __restrict__ Ximg,
                 const float* __restrict__ Xehr,
                 float* __restrict__ planes,
                 float* __restrict__ sqn) {
    const int tid = threadIdx.x;
    const int bid = blockIdx.x;

    if (bid < 2) {                       // sq-norm blocks: one row per thread
        const int m = bid;
        const float* __restrict__ X = m ? Xehr : Ximg;
        const float4* xr = (const float4*)(X + (size_t)tid * ND);
        float acc = 0.0f;
#pragma unroll 8
        for (int t = 0; t < ND / 4; ++t) {
            const float4 v = xr[t];
            acc += v.x * v.x + v.y * v.y + v.z * v.z + v.w * v.w;
        }
        sqn[m * NB + tid] = acc;
        return;
    }

    __shared__ float S[(64 + 128) * PITCH];   // A: rows 0..63, B: rows 64..191 (24.6 KB)

    const int cb   = bid - 2;
    const int m    = cb >> 8;         // 0 = img, 1 = ehr
    const int r    = cb & 255;
    const int tile = r >> 5;          // 0..7
    const int kc   = r & 31;          // 0..31
    const int ta   = tile >> 1;       // 0..3 : A strip (64 rows)
    const int tb   = tile & 1;        // 0..1 : B strip (128 rows)
    const float* __restrict__ X = m ? Xehr : Ximg;
    const int c0 = kc * CHF;

    // stage A 64x6 f4 + B 128x6 f4 = 1152 float4, XOR-swizzled slots
    for (int p = 0; p < 5; ++p) {
        const int idx = tid + (p << 8);
        if (idx < 1152) {
            int row, c4, grow, base;
            if (idx < 384) { row = idx / 6; c4 = idx - row * 6; grow = ta * 64 + row; base = 0; }
            else { const int t2 = idx - 384; row = t2 / 6; c4 = t2 - row * 6; grow = tb * 128 + row; base = 64 * PITCH; }
            const float4 v = *(const float4*)(&X[(size_t)grow * ND + c0 + c4 * 4]);
            *(float4*)(&S[base + row * PITCH + ((c4 ^ swz(row)) << 2)]) = v;
        }
    }
    __syncthreads();

    const int li = tid >> 4;          // A rows 4li..4li+3
    const int lj = tid & 15;          // B rows 8lj..8lj+7
    int sA[4], sB[8];
#pragma unroll
    for (int a = 0; a < 4; ++a) sA[a] = swz(4 * li + a);
#pragma unroll
    for (int b = 0; b < 8; ++b) sB[b] = swz(8 * lj + b);

    float acc[4][8];
#pragma unroll
    for (int a = 0; a < 4; ++a)
#pragma unroll
        for (int b = 0; b < 8; ++b) acc[a][b] = 0.0f;

#pragma unroll
    for (int q = 0; q < 6; ++q) {
        float4 av[4], bv[8];
#pragma unroll
        for (int a = 0; a < 4; ++a)
            av[a] = *(const float4*)(&S[(4 * li + a) * PITCH + ((q ^ sA[a]) << 2)]);
#pragma unroll
        for (int b = 0; b < 8; ++b)
            bv[b] = *(const float4*)(&S[64 * PITCH + (8 * lj + b) * PITCH + ((q ^ sB[b]) << 2)]);
#pragma unroll
        for (int a = 0; a < 4; ++a)
#pragma unroll
            for (int b = 0; b < 8; ++b)
                acc[a][b] += av[a].x * bv[b].x + av[a].y * bv[b].y +
                             av[a].z * bv[b].z + av[a].w * bv[b].w;
    }

    float* P = planes + (((size_t)m * NKC + kc) << 16);
#pragma unroll
    for (int a = 0; a < 4; ++a) {
        const int gi = ta * 64 + 4 * li + a;
        const int cb0 = tb * 128 + 8 * lj;
        float4 v0, v1;
        v0.x = acc[a][0]; v0.y = acc[a][1]; v0.z = acc[a][2]; v0.w = acc[a][3];
        v1.x = acc[a][4]; v1.y = acc[a][5]; v1.z = acc[a][6]; v1.w = acc[a][7];
        *(float4*)(&P[(size_t)gi * NB + cb0])     = v0;
        *(float4*)(&P[(size_t)gi * NB + cb0 + 4]) = v1;
    }
}

// ---------------- k2: triplet loss per row i ----------------
// 256 blocks x 512 threads (two j-halves). d^2 = sq_i + sq_k - 2*dot (reference's
// own form). Ordered-pair sum = 2x reference; j==k contributes exactly MARGIN_F
// (diff = -0.0 path) and j==i contributes an exactly-reproducible term -> both
// removed post-loop. Plain store; no cross-block sync.
__global__ __launch_bounds__(512)
void triplet_kernel(const float* __restrict__ planes,
                    const float* __restrict__ sqn,
                    float* __restrict__ partials) {
    __shared__ float Es[NB], Gs[NB];
    __shared__ float pg[2][NB], pe[2][NB];
    __shared__ float wred[8];

    const int tid = threadIdx.x;
    const int i   = blockIdx.x;
    const int k   = tid & 255;
    const int h   = tid >> 8;

    // dot row i: each (h,k) sums 16 planes per matrix
    float sg = 0.0f, se = 0.0f;
#pragma unroll
    for (int p = 0; p < 16; ++p) {
        const int pp = h * 16 + p;
        sg += planes[((size_t)pp << 16) + (size_t)i * NB + k];
        se += planes[((size_t)(NKC + pp) << 16) + (size_t)i * NB + k];
    }
    pg[h][k] = sg; pe[h][k] = se;
    __syncthreads();
    if (h == 0) {
        const float dg = pg[0][k] + pg[1][k];
        const float de = pe[0][k] + pe[1][k];
        const float d2g = sqn[i] + sqn[k] - 2.0f * dg;
        const float d2e = sqn[NB + i] + sqn[NB + k] - 2.0f * de;
        Gs[k] = (d2g > 0.0f) ? sqrtf(d2g) : 0.0f;
        Es[k] = (d2e > 0.0f) ? sqrtf(d2e) : 0.0f;
    }
    __syncthreads();

    const float ek = Es[k];
    const float gk = Gs[k];

    float local = 0.0f;
    const int j0 = h << 7;
#pragma unroll 8
    for (int jj = 0; jj < 128; ++jj) {
        const int j = j0 + jj;
        const float diff = Gs[j] - gk;
        const float s = (Es[j] < ek) ? diff : -diff;   // tie (j==k) -> -0.0 path
        local += fmaxf(MARGIN_F + s, 0.0f);
    }
    // j==k iteration added exactly MARGIN_F -> remove
    if (((k >> 7) == h) && (k != i)) local -= MARGIN_F;
    // j==i iteration added an exactly-reproducible term -> remove
    if (((i >> 7) == h) && (k != i)) {
        const float diff = Gs[i] - gk;
        const float s = (Es[i] < ek) ? diff : -diff;
        local -= fmaxf(MARGIN_F + s, 0.0f);
    }
    if (k == i) local = 0.0f;

    // 8-wave block reduce
    for (int off = 32; off > 0; off >>= 1) local += __shfl_down(local, off, 64);
    const int wid = tid >> 6;
    const int lane = tid & 63;
    if (lane == 0) wred[wid] = local;
    __syncthreads();

    if (tid == 0) {
        float s = 0.0f;
#pragma unroll
        for (int w = 0; w < 8; ++w) s += wred[w];
        partials[i] = s;
    }
}

// ---------------- k3: final reduction (double, fixed order) ----------------
__global__ __launch_bounds__(256)
void reduce_kernel(const float* __restrict__ partials,
                   float* __restrict__ out) {
    const int tid = threadIdx.x;
    double v = (double)partials[tid];
    for (int off = 32; off > 0; off >>= 1) v += __shfl_down(v, off, 64);
    __shared__ double ds4[4];
    const int wid = tid >> 6;
    const int lane = tid & 63;
    if (lane == 0) ds4[wid] = v;
    __syncthreads();
    if (tid == 0) {
        const double total = ds4[0] + ds4[1] + ds4[2] + ds4[3];
        // x0.5 ordered->unordered pairs, / num_triplets (256*255*254/2)
        out[0] = (float)(total * 0.5 / 8290560.0);
    }
}

extern "C" void kernel_launch(void* const* d_in, const int* in_sizes, int n_in,
                              void* d_out, int out_size, void* d_ws, size_t ws_size,
                              hipStream_t stream) {
    const float* img = (const float*)d_in[0];  // img_tokens (256,768)
    const float* ehr = (const float*)d_in[1];  // ehr_tokens (256,768)
    float* out = (float*)d_out;

    float* planes   = (float*)d_ws;                       // 2*32*256*256 f32 = 16.8 MB
    float* sqn      = planes + 2 * NKC * NB * NB;         // 512 f32
    float* partials = sqn + 2 * NB;                       // 256 f32

    dist_kernel<<<dim3(514), 256, 0, stream>>>(img, ehr, planes, sqn);
    triplet_kernel<<<dim3(NB), 512, 0, stream>>>(planes, sqn, partials);
    reduce_kernel<<<dim3(1), 256, 0, stream>>>(partials, out);
}

// Round 8
// 24.407 us; speedup vs baseline: 1.6156x; 1.6156x over previous
//
#include <hip/hip_runtime.h>
#include <math.h>

#define NB 256
#define ND 768
#define MARGIN_F 0.2f
#define NKC 16            // k-chunks per matrix
#define KCF 48            // floats per k-chunk (12 float4)
#define PITCH 64          // LDS row pitch in floats (padded from 48)

// ---------------- k1: d^2 partial planes [2][16][256][256] ----------------
// 512 blocks = 2 matrices x 16 (64x64) tiles x 16 k-chunks; 4x4 register tiling.
// Block 0 also zeroes out[0] (ordered before k2 by the kernel boundary), so k2
// can accumulate into it with plain atomics and no third kernel.
__global__ __launch_bounds__(256)
void dist_kernel(const float* __restrict__ Ximg,
                 const float* __restrict__ Xehr,
                 float* __restrict__ planes,
                 float* __restrict__ out) {
    __shared__ float As[64 * PITCH];
    __shared__ float Bs[64 * PITCH];

    const int tid = threadIdx.x;
    const int bid = blockIdx.x;
    if (bid == 0 && tid == 0) out[0] = 0.0f;

    const int m    = bid >> 8;        // 0 = img, 1 = ehr
    const int r    = bid & 255;
    const int tile = r >> 4;          // 4x4 grid of 64x64 tiles
    const int kc   = r & 15;
    const int ti   = tile >> 2;
    const int tj   = tile & 3;
    const float* __restrict__ X = m ? Xehr : Ximg;
    const int base_col = kc * KCF;

    // stage 64 rows x 12 float4 per side (768 f4 = 3 x 256), XOR-swizzled
#pragma unroll
    for (int p = 0; p < 3; ++p) {
        const int idx = tid + (p << 8);          // 0..767
        const int row = idx / 12;                // 0..63
        const int c4  = idx - row * 12;          // 0..11
        const int sw  = (row >> 2) & 7;
        const float4 va = *(const float4*)(&X[(size_t)(ti * 64 + row) * ND + base_col + c4 * 4]);
        *(float4*)(&As[row * PITCH + ((c4 ^ sw) << 2)]) = va;
        const float4 vb = *(const float4*)(&X[(size_t)(tj * 64 + row) * ND + base_col + c4 * 4]);
        *(float4*)(&Bs[row * PITCH + ((c4 ^ sw) << 2)]) = vb;
    }
    __syncthreads();

    const int li = tid >> 4;          // rows 4li..4li+3
    const int lj = tid & 15;          // cols 4lj..4lj+3
    const int swa = li & 7;
    const int swb = lj & 7;

    float acc[4][4];
#pragma unroll
    for (int a = 0; a < 4; ++a)
#pragma unroll
        for (int b = 0; b < 4; ++b) acc[a][b] = 0.0f;

#pragma unroll 4
    for (int q = 0; q < 12; ++q) {
        float4 av[4], bv[4];
#pragma unroll
        for (int a = 0; a < 4; ++a)
            av[a] = *(const float4*)(&As[(4 * li + a) * PITCH + ((q ^ swa) << 2)]);
#pragma unroll
        for (int b = 0; b < 4; ++b)
            bv[b] = *(const float4*)(&Bs[(4 * lj + b) * PITCH + ((q ^ swb) << 2)]);
#pragma unroll
        for (int a = 0; a < 4; ++a)
#pragma unroll
            for (int b = 0; b < 4; ++b) {
                const float d0 = av[a].x - bv[b].x;
                const float d1 = av[a].y - bv[b].y;
                const float d2 = av[a].z - bv[b].z;
                const float d3 = av[a].w - bv[b].w;
                acc[a][b] += d0 * d0 + d1 * d1 + d2 * d2 + d3 * d3;
            }
    }

    float* P = planes + (((size_t)m * NKC + kc) << 16);
#pragma unroll
    for (int a = 0; a < 4; ++a) {
        const int gi = ti * 64 + 4 * li + a;
        float4 v;
        v.x = acc[a][0]; v.y = acc[a][1]; v.z = acc[a][2]; v.w = acc[a][3];
        *(float4*)(&P[(size_t)gi * NB + tj * 64 + 4 * lj]) = v;   // coalesced f4 store
    }
}

// ---------------- k2: triplet loss per row i + atomic commit ----------------
// 256 blocks (one per i) x 512 threads (two j-halves). Ordered-pair form:
// term(j,k) symmetric -> sum over all ordered pairs = 2x reference; j==k term
// is exactly 0; j==i term is exactly relu(M - g_ik) (d_ii == 0 bit-exactly),
// removed post-loop. Each block atomically adds its scaled partial to out[0]
// (zeroed by k1): plain device-scope f32 atomics, no release/acquire storm.
__global__ __launch_bounds__(512)
void triplet_kernel(const float* __restrict__ planes,
                    float* __restrict__ out) {
    __shared__ __align__(16) float Es[NB];
    __shared__ __align__(16) float Gs[NB];
    __shared__ float pg[2][NB], pe[2][NB];
    __shared__ float wred[8];

    const int tid = threadIdx.x;
    const int i   = blockIdx.x;
    const int k   = tid & 255;
    const int h   = tid >> 8;           // j-half / plane-half

    // rebuild distance row i: each (h,k) sums 8 planes per matrix
    float sg = 0.0f, se = 0.0f;
#pragma unroll
    for (int p = 0; p < 8; ++p) {
        const int pp = h * 8 + p;
        sg += planes[(((size_t)0 * NKC + pp) << 16) + (size_t)i * NB + k];
        se += planes[(((size_t)1 * NKC + pp) << 16) + (size_t)i * NB + k];
    }
    pg[h][k] = sg; pe[h][k] = se;
    __syncthreads();
    if (h == 0) {
        const float g2 = pg[0][k] + pg[1][k];
        const float e2 = pe[0][k] + pe[1][k];
        Gs[k] = (g2 > 0.0f) ? sqrtf(g2) : 0.0f;
        Es[k] = (e2 > 0.0f) ? sqrtf(e2) : 0.0f;
    }
    __syncthreads();

    const float ek = Es[k];
    const float gk = Gs[k];

    float local = 0.0f;
    const int j0 = h << 7;
#pragma unroll 4
    for (int jj4 = 0; jj4 < 32; ++jj4) {
        const float4 ej4 = *(const float4*)(&Es[j0 + 4 * jj4]);  // uniform -> broadcast
        const float4 gj4 = *(const float4*)(&Gs[j0 + 4 * jj4]);
        const float ejv[4] = {ej4.x, ej4.y, ej4.z, ej4.w};
        const float gjv[4] = {gj4.x, gj4.y, gj4.z, gj4.w};
#pragma unroll
        for (int u = 0; u < 4; ++u) {
            const float diff = gjv[u] - gk;
            const float a = diff + MARGIN_F;     // e_ij < e_ik
            const float b = MARGIN_F - diff;     // e_ik < e_ij
            const float cc = fabsf(diff);        // tie (incl. j==k -> 0)
            const float sel = (ejv[u] < ek) ? a : ((ek < ejv[u]) ? b : cc);
            local += fmaxf(sel, 0.0f);
        }
    }
    if (((i >> 7) == h) && (k != i)) local -= fmaxf(MARGIN_F - gk, 0.0f);
    if (k == i) local = 0.0f;

    // 8-wave block reduce
    for (int off = 32; off > 0; off >>= 1) local += __shfl_down(local, off, 64);
    const int wid = tid >> 6;
    const int lane = tid & 63;
    if (lane == 0) wred[wid] = local;
    __syncthreads();

    if (tid == 0) {
        float s = 0.0f;
#pragma unroll
        for (int w = 0; w < 8; ++w) s += wred[w];
        // x0.5 ordered->unordered pairs, / num_triplets (256*255*254/2)
        atomicAdd(out, s * (float)(0.5 / 8290560.0));
    }
}

extern "C" void kernel_launch(void* const* d_in, const int* in_sizes, int n_in,
                              void* d_out, int out_size, void* d_ws, size_t ws_size,
                              hipStream_t stream) {
    const float* img = (const float*)d_in[0];  // img_tokens (256,768)
    const float* ehr = (const float*)d_in[1];  // ehr_tokens (256,768)
    float* out = (float*)d_out;

    float* planes = (float*)d_ws;              // 2*16*256*256 f32 = 8 MB

    dist_kernel<<<dim3(512), 256, 0, stream>>>(img, ehr, planes, out);
    triplet_kernel<<<dim3(NB), 512, 0, stream>>>(planes, out);
}